// Round 7
// baseline (234.417 us; speedup 1.0000x reference)
//
#include <hip/hip_runtime.h>
#include <hip/hip_cooperative_groups.h>

namespace cg = cooperative_groups;

// y[e] = W2 . relu(W1 . concat(z[src[e]], z[dst[e]]) + b1) + b2
// N=50000, D=128, H=512, E=500000. 131 GFLOP in GEMM1.
// R14: single cooperative launch. Across R0-R13 the (total - edge_kernel)
// gap was a constant ~60us while the edge kernel went 216->121us: that is
// 2-launch pipeline overhead, not prep work (prep arithmetic: 42MB @ 6TB/s
// ~= 7us). Merge prep into the edge kernel behind a grid-wide sync
// (hipLaunchCooperativeKernel; 256 blocks x 512 thr, validated 1-2
// blocks/CU). Phase 0: grid-stride z->bf16 (zb), W1->w1s fragment
// swizzle, out <- b2 prefill. grid.sync(). Phase 1: R13 loop VERBATIM
// (121us standalone): persistent blocks, W1-in-regs (128/wave),
// operand-swapped MFMA (C row=h col=edge; in-reg h-reduce + 2 shuffles),
// mid-tile gather issue via global_load_lds, source-side XOR swizzle,
// b1 in acc init, atomic epilogue (8 adds/edge, out prefilled w/ b2),
// single barrier + vmcnt(8) ledger per tile.
// breg loads AFTER grid.sync (dep on w1s); vmcnt(0) drain re-baselines
// the ledger. No early-exit before the sync (grid=256 <= ntiles).

typedef __bf16 bf16x8 __attribute__((ext_vector_type(8)));
typedef float f32x4 __attribute__((ext_vector_type(4)));

__device__ __forceinline__ unsigned short f2b(float f) {
    unsigned int u = __float_as_uint(f);
    u = (u + 0x7fffu + ((u >> 16) & 1u)) >> 16;   // RNE
    return (unsigned short)u;
}

__device__ __forceinline__ void gload_lds16(const unsigned short* g, unsigned short* l) {
    __builtin_amdgcn_global_load_lds(
        (const __attribute__((address_space(1))) unsigned int*)g,
        (__attribute__((address_space(3))) unsigned int*)l, 16, 0, 0);
}

// zb: z as bf16 [N][128].  w1s: W1 swizzled to MFMA fragment order:
// w1s[(hblk*8 + kc)*512 + lane*8 + t] = bf16(W1[hblk*16 + (lane&15)][kc*32 + (lane>>4)*8 + t])
__global__ __launch_bounds__(512, 2)
void fused_kernel(const float* __restrict__ z, const int* __restrict__ ei,
                  const float* __restrict__ W1, const float* __restrict__ b1,
                  const float* __restrict__ W2, const float* __restrict__ b2p,
                  unsigned short* __restrict__ zb, unsigned short* __restrict__ w1s,
                  float* __restrict__ out, int E, int NZ, int ntiles) {
    __shared__ unsigned short ldsA[2][64 * 256];  // 64 KB, dbuf A tiles
    __shared__ float ldsB1[512];                  // 2 KB staged b1

    const int tid  = threadIdx.x;
    const int lane = tid & 63;
    const int w    = tid >> 6;        // 0..7 : 64-h slice of H=512
    const int l15  = lane & 15;
    const int l4   = lane >> 4;
    const int G    = gridDim.x;
    const int t0   = blockIdx.x;

    // ================= phase 0: prep (grid-stride) =================
    {
        const int nz4   = NZ / 4;
        const int nw    = 256 * 64;       // (hblk*8+kc) x lane
        const int nout4 = E / 4;
        const int total = nz4 + nw + nout4;
        const int stride = G * 512;
        const float b2v = b2p[0];
        for (int idx = t0 * 512 + tid; idx < total; idx += stride) {
            if (idx < nz4) {
                float4 v = ((const float4*)z)[idx];
                ushort4 o;
                o.x = f2b(v.x); o.y = f2b(v.y); o.z = f2b(v.z); o.w = f2b(v.w);
                ((ushort4*)zb)[idx] = o;
            } else if (idx < nz4 + nw) {
                int u = idx - nz4;            // 0..16383
                int ln = u & 63;
                int blk  = u >> 6;            // hblk*8 + kc
                int h  = (blk >> 3) * 16 + (ln & 15);
                int kb = (blk & 7) * 32 + (ln >> 4) * 8;
                const float* src = W1 + h * 256 + kb;
                ushort4 o0, o1;
                float4 v0 = *(const float4*)(src);
                float4 v1 = *(const float4*)(src + 4);
                o0.x = f2b(v0.x); o0.y = f2b(v0.y); o0.z = f2b(v0.z); o0.w = f2b(v0.w);
                o1.x = f2b(v1.x); o1.y = f2b(v1.y); o1.z = f2b(v1.z); o1.w = f2b(v1.w);
                ushort4* dst = (ushort4*)(w1s + u * 8);
                dst[0] = o0; dst[1] = o1;
            } else {
                ((float4*)out)[idx - nz4 - nw] = (float4){b2v, b2v, b2v, b2v};
            }
        }
        ldsB1[tid] = b1[tid];             // block-local stage (sync covers it)
    }

    cg::this_grid().sync();               // zb/w1s/out visible device-wide

    // ================= phase 1: edge MLP (R13 loop) =================
    // ---- persistent W1: wave w holds hblk w*4..w*4+3, full K, in regs ----
    uint4 breg[4][8];                 // 128 regs
    #pragma unroll
    for (int j = 0; j < 4; ++j)
        #pragma unroll
        for (int kc = 0; kc < 8; ++kc)
            breg[j][kc] = *(const uint4*)(w1s + (((w * 4 + j) * 8 + kc) << 9) + lane * 8);

    // w2 per lane: h = w*64 + j*16 + l4*4 + r  -> f32x4 per j (16 regs)
    f32x4 w2v[4];
    #pragma unroll
    for (int j = 0; j < 4; ++j)
        w2v[j] = *(const f32x4*)&W2[w * 64 + j * 16 + l4 * 4];

    // gather: instr q covers rows m=(w*8+q*2)+rsub; lane L writes LDS slot
    // L&31 of the row pair; source slot pre-swizzled s15 = l15 ^ (m&7).
    const int side = (lane >> 4) & 1;
    const int rsub = lane >> 5;
    const int swz  = l15 & 7;

#define ISSUE_GATHER(BUF)                                                     \
    do {                                                                      \
        _Pragma("unroll")                                                     \
        for (int q_ = 0; q_ < 4; ++q_) {                                      \
            int m_   = w * 8 + q_ * 2 + rsub;                                 \
            int s15_ = l15 ^ (m_ & 7);                                        \
            gload_lds16(zb + (((long)ival[q_]) << 7) + (s15_ << 3),           \
                        &ldsA[BUF][(w * 8 + q_ * 2) << 8]);                   \
        }                                                                     \
    } while (0)

    // drain staging loads (breg/w2) so the vmcnt ledger starts clean
    asm volatile("s_waitcnt vmcnt(0) lgkmcnt(0)" ::: "memory");

    // ---- prologue: idx(T0) -> gather(T0) -> idx(T1) -> 4 zero-atomics ----
    int ival[4];
    #pragma unroll
    for (int q = 0; q < 4; ++q) {
        int e = t0 * 64 + w * 8 + q * 2 + rsub;
        e = (e < E) ? e : (E - 1);
        ival[q] = ei[side * E + e];
    }
    ISSUE_GATHER(0);
    asm volatile("" ::: "memory");     // pin: idx(T1) stays AFTER gathers
    {
        int t1 = t0 + G;
        #pragma unroll
        for (int q = 0; q < 4; ++q) {
            int e = t1 * 64 + w * 8 + q * 2 + rsub;
            e = (e < E) ? e : (E - 1);
            ival[q] = ei[side * E + e];
        }
    }
    asm volatile("" ::: "memory");     // pin: zero-atomics AFTER idx(T1)
    if (l4 == 0) {                     // 4 queue-padding atomics (add 0.0f)
        #pragma unroll
        for (int i = 0; i < 4; ++i)
            atomicAdd(&out[t0 * 64 + i * 16 + l15], 0.0f);
    }

    int cur = 0;
    for (int t = t0; t < ntiles; t += G) {
        // own 4 gathers are oldest; 4 idx + 4 atomics are newer -> vmcnt(8)
        asm volatile("s_waitcnt vmcnt(8)" ::: "memory");
        __builtin_amdgcn_s_barrier();
        asm volatile("" ::: "memory");

        const unsigned short* bufc = &ldsA[cur][0];

        // acc init = b1 (acc ends as W1.x + b1); C row=h, col=edge
        f32x4 acc[4][4];                  // [edge-tile i][h-tile j]
        {
            f32x4 b1t[4];
            #pragma unroll
            for (int j = 0; j < 4; ++j)
                b1t[j] = *(const f32x4*)&ldsB1[w * 64 + j * 16 + l4 * 4];
            #pragma unroll
            for (int i = 0; i < 4; i++)
                #pragma unroll
                for (int j = 0; j < 4; j++) acc[i][j] = b1t[j];
        }

        __builtin_amdgcn_s_setprio(1);
        #pragma unroll
        for (int kc = 0; kc < 4; ++kc) {
            bf16x8 a[4];
            #pragma unroll
            for (int i = 0; i < 4; ++i)
                a[i] = *(const bf16x8*)&bufc[((l15 + 16 * i) << 8) + ((((kc << 2) + l4) ^ swz) << 3)];
            #pragma unroll
            for (int i = 0; i < 4; ++i)
                #pragma unroll
                for (int j = 0; j < 4; ++j)
                    acc[i][j] = __builtin_amdgcn_mfma_f32_16x16x32_bf16(
                        *(const bf16x8*)&breg[j][kc], a[i], acc[i][j], 0, 0, 0);
        }
        __builtin_amdgcn_s_setprio(0);

        // issue next tile's gathers (HBM latency hides under kc4..7)
        ISSUE_GATHER(cur ^ 1);
        asm volatile("" ::: "memory");

        __builtin_amdgcn_s_setprio(1);
        #pragma unroll
        for (int kc = 4; kc < 8; ++kc) {
            bf16x8 a[4];
            #pragma unroll
            for (int i = 0; i < 4; ++i)
                a[i] = *(const bf16x8*)&bufc[((l15 + 16 * i) << 8) + ((((kc << 2) + l4) ^ swz) << 3)];
            #pragma unroll
            for (int i = 0; i < 4; ++i)
                #pragma unroll
                for (int j = 0; j < 4; ++j)
                    acc[i][j] = __builtin_amdgcn_mfma_f32_16x16x32_bf16(
                        *(const bf16x8*)&breg[j][kc], a[i], acc[i][j], 0, 0, 0);
        }
        __builtin_amdgcn_s_setprio(0);

        // tail: idx for tile t+2G (consumed by NEXT iter's gather-issue)
        {
            int tt = t + 2 * G;
            #pragma unroll
            for (int q = 0; q < 4; ++q) {
                int e = tt * 64 + w * 8 + q * 2 + rsub;
                e = (e < E) ? e : (E - 1);
                ival[q] = ei[side * E + e];
            }
        }
        asm volatile("" ::: "memory");  // pin: epilogue atomics AFTER idx

        // epilogue: y-partial = sum_{h in slice} relu(acc)*w2 ; 2 shuffles;
        // wave adds its partial straight into out[e] (out prefilled w/ b2)
        float s4[4];
        #pragma unroll
        for (int i = 0; i < 4; i++) {
            float s = 0.f;
            #pragma unroll
            for (int j = 0; j < 4; j++)
                #pragma unroll
                for (int r = 0; r < 4; r++)
                    s = fmaf(fmaxf(acc[i][j][r], 0.f), w2v[j][r], s);
            s += __shfl_xor(s, 16);
            s += __shfl_xor(s, 32);
            s4[i] = s;
        }
        #pragma unroll
        for (int i = 0; i < 4; i++) {
            int e = t * 64 + i * 16 + l15;
            if (l4 == 0 && e < E) atomicAdd(&out[e], s4[i]);
        }

        cur ^= 1;
    }
#undef ISSUE_GATHER
}

extern "C" void kernel_launch(void* const* d_in, const int* in_sizes, int n_in,
                              void* d_out, int out_size, void* d_ws, size_t ws_size,
                              hipStream_t stream) {
    const float* z  = (const float*)d_in[0];
    const int*   ei = (const int*)d_in[1];
    const float* W1 = (const float*)d_in[2];
    const float* b1 = (const float*)d_in[3];
    const float* W2 = (const float*)d_in[4];
    const float* b2 = (const float*)d_in[5];
    float* out = (float*)d_out;

    int E  = in_sizes[1] / 2;   // 500000
    int NZ = in_sizes[0];       // 6400000 = N*D

    unsigned short* zb  = (unsigned short*)d_ws;       // 12.8 MB
    unsigned short* w1s = zb + NZ;                     // 256 KB (swizzled W1)

    int ntiles = (E + 63) / 64;                        // 7813

    void* args[] = { (void*)&z, (void*)&ei, (void*)&W1, (void*)&b1,
                     (void*)&W2, (void*)&b2, (void*)&zb, (void*)&w1s,
                     (void*)&out, (void*)&E, (void*)&NZ, (void*)&ntiles };
    hipLaunchCooperativeKernel((const void*)fused_kernel,
                               dim3(256), dim3(512), args, 0, stream);
}

// Round 8
// 190.490 us; speedup vs baseline: 1.2306x; 1.2306x over previous
//
#include <hip/hip_runtime.h>

// y[e] = W2 . relu(W1 . concat(z[src[e]], z[dst[e]]) + b1) + b2
// N=50000, D=128, H=512, E=500000. 131 GFLOP in GEMM1.
// R15: R13 two-launch structure (R14's cooperative fusion regressed:
// the ~55us total-minus-kernel gap is harness reset dispatches, not our
// launches) + MFMA shape 16x16x32 -> 32x32x16.
// Same tile algebra per wave (64e x 64h: breg 128 regs, acc 64, 32
// ds_read_b128/tile) but 512 MFMA/tile x 8.07cyc = 4.13K matrix cyc
// (-17% vs 1024 x 4.86) and half the MFMA issue slots at 2 waves/SIMD.
// Epilogue: C col=lane&31 (32-edge span) -> 1 shuffle (xor32) + 2
// atomics/wave (ledger -> vmcnt(6)).
// Layouts (32x32x16): A/B frag: row|col=lane&31, k=(lane>>5)*8+t.
// C/D: col=lane&31, row=(reg&3)+8*(reg>>2)+4*(lane>>5), reg in [0,16).
// LDS A-tile: 64 rows x 32 16B-slots; logical k-slot s=kst*2+hi stored
// at slot (s&16)|((s&15)^(r&7)) via pre-swizzled GATHER SOURCE (linear
// LDS dest, source-permute == read-permute). Kept from R13: persistent
// blocks (grid=256), W1-in-regs, mid-tile gather issue, b1 in acc init,
// atomic epilogue into b2-prefilled out, single barrier + vmcnt ledger.

typedef __bf16 bf16x8 __attribute__((ext_vector_type(8)));
typedef float f32x4  __attribute__((ext_vector_type(4)));
typedef float f32x16 __attribute__((ext_vector_type(16)));

__device__ __forceinline__ unsigned short f2b(float f) {
    unsigned int u = __float_as_uint(f);
    u = (u + 0x7fffu + ((u >> 16) & 1u)) >> 16;   // RNE
    return (unsigned short)u;
}

__device__ __forceinline__ void gload_lds16(const unsigned short* g, unsigned short* l) {
    __builtin_amdgcn_global_load_lds(
        (const __attribute__((address_space(1))) unsigned int*)g,
        (__attribute__((address_space(3))) unsigned int*)l, 16, 0, 0);
}

// zb: z as bf16 [N][128].  w1s: W1 in 32x32x16 A-fragment order:
// w1s[(hb*16 + kst)*512 + lane*8 + t]
//   = bf16(W1[hb*32 + (lane&31)][kst*16 + (lane>>5)*8 + t]),  hb,kst in 0..15
// Also pre-fills out[] with b2 (atomicAdd target).
__global__ void prep_kernel(const float* __restrict__ z, const float* __restrict__ W1,
                            const float* __restrict__ b2p,
                            unsigned short* __restrict__ zb, unsigned short* __restrict__ w1s,
                            float* __restrict__ outz, int nz4, int nout4) {
    int stride = gridDim.x * blockDim.x;
    const int nw = 256 * 64;   // (hb*16+kst) x lane
    const int total = nz4 + nw + nout4;
    const float b2v = b2p[0];
    for (int idx = blockIdx.x * blockDim.x + threadIdx.x; idx < total; idx += stride) {
        if (idx < nz4) {
            float4 v = ((const float4*)z)[idx];
            ushort4 o;
            o.x = f2b(v.x); o.y = f2b(v.y); o.z = f2b(v.z); o.w = f2b(v.w);
            ((ushort4*)zb)[idx] = o;
        } else if (idx < nz4 + nw) {
            int u = idx - nz4;            // 0..16383
            int lane = u & 63;
            int blk  = u >> 6;            // hb*16 + kst
            int h  = (blk >> 4) * 32 + (lane & 31);
            int kb = (blk & 15) * 16 + (lane >> 5) * 8;
            const float* src = W1 + h * 256 + kb;
            ushort4 o0, o1;
            float4 v0 = *(const float4*)(src);
            float4 v1 = *(const float4*)(src + 4);
            o0.x = f2b(v0.x); o0.y = f2b(v0.y); o0.z = f2b(v0.z); o0.w = f2b(v0.w);
            o1.x = f2b(v1.x); o1.y = f2b(v1.y); o1.z = f2b(v1.z); o1.w = f2b(v1.w);
            ushort4* dst = (ushort4*)(w1s + u * 8);
            dst[0] = o0; dst[1] = o1;
        } else {
            ((float4*)outz)[idx - nz4 - nw] = (float4){b2v, b2v, b2v, b2v};
        }
    }
}

__global__ __launch_bounds__(512, 2)
void edge_mlp_kernel(const int* __restrict__ ei, const unsigned short* __restrict__ zb,
                     const unsigned short* __restrict__ w1s,
                     const float* __restrict__ b1, const float* __restrict__ W2,
                     float* __restrict__ out, int E, int ntiles) {
    __shared__ unsigned short ldsA[2][64 * 256];  // 64 KB, dbuf A tiles
    __shared__ float ldsB1[512];                  // 2 KB staged b1
    __shared__ float ldsW2[512];                  // 2 KB staged W2

    const int tid  = threadIdx.x;
    const int lane = tid & 63;
    const int w    = tid >> 6;        // 0..7 : 64-h slice of H=512
    const int l31  = lane & 31;
    const int hi   = lane >> 5;       // 0/1 : k-half within frag, C row-group
    const int G    = gridDim.x;
    const int t0   = blockIdx.x;
    if (t0 >= ntiles) return;

    ldsB1[tid] = b1[tid];
    ldsW2[tid] = W2[tid];

    // ---- persistent W1: wave w holds hb w*2, w*2+1 (64 h), in regs ----
    uint4 breg[2][16];                // 128 regs
    #pragma unroll
    for (int j = 0; j < 2; ++j)
        #pragma unroll
        for (int kst = 0; kst < 16; ++kst)
            breg[j][kst] = *(const uint4*)(w1s + (((w * 2 + j) * 16 + kst) << 9) + lane * 8);

    // gather: instr q covers rows m=(w*8+q*2)+hi; lane L writes LDS slot
    // L&31 of the row pair; source k-slot pre-swizzled: side*16 + (l15^(m&7)).
    const int side = (lane >> 4) & 1;
    const int l15  = lane & 15;
    const int swz3 = (l31 & 7) << 3;  // read-side XOR on the low-4 slot bits (x8 elems)

#define ISSUE_GATHER(BUF)                                                     \
    do {                                                                      \
        _Pragma("unroll")                                                     \
        for (int q_ = 0; q_ < 4; ++q_) {                                      \
            int m_   = w * 8 + q_ * 2 + hi;                                   \
            int s15_ = l15 ^ (m_ & 7);                                        \
            gload_lds16(zb + (((long)ival[q_]) << 7) + (s15_ << 3),           \
                        &ldsA[BUF][(w * 8 + q_ * 2) << 8]);                   \
        }                                                                     \
    } while (0)

    // drain staging loads (breg/b1/W2) so the vmcnt ledger starts clean
    asm volatile("s_waitcnt vmcnt(0) lgkmcnt(0)" ::: "memory");

    // ---- prologue: idx(T0) -> gather(T0) -> idx(T1) -> 2 zero-atomics ----
    int ival[4];
    #pragma unroll
    for (int q = 0; q < 4; ++q) {
        int e = t0 * 64 + w * 8 + q * 2 + hi;
        e = (e < E) ? e : (E - 1);
        ival[q] = ei[side * E + e];
    }
    ISSUE_GATHER(0);
    asm volatile("" ::: "memory");     // pin: idx(T1) stays AFTER gathers
    {
        int t1 = t0 + G;
        #pragma unroll
        for (int q = 0; q < 4; ++q) {
            int e = t1 * 64 + w * 8 + q * 2 + hi;
            e = (e < E) ? e : (E - 1);
            ival[q] = ei[side * E + e];
        }
    }
    asm volatile("" ::: "memory");     // pin: zero-atomics AFTER idx(T1)
    if (hi == 0) {                     // 2 queue-padding atomics (add 0.0f)
        atomicAdd(&out[t0 * 64 + l31], 0.0f);
        atomicAdd(&out[t0 * 64 + 32 + l31], 0.0f);
    }

    int cur = 0;
    for (int t = t0; t < ntiles; t += G) {
        // own 4 gathers are oldest; 4 idx + 2 atomics are newer -> vmcnt(6)
        asm volatile("s_waitcnt vmcnt(6)" ::: "memory");
        __builtin_amdgcn_s_barrier();
        asm volatile("" ::: "memory");

        const unsigned short* bufc = &ldsA[cur][0];

        // acc init = b1 (acc ends as W1.x + b1); C row=h, col=edge
        // h(j,reg) = w*64 + j*32 + (reg&3) + 8*(reg>>2) + 4*hi
        f32x16 acc[2][2];                 // [edge-blk i][h-blk j]
        #pragma unroll
        for (int j = 0; j < 2; ++j)
            #pragma unroll
            for (int q = 0; q < 4; ++q) {
                f32x4 b = *(const f32x4*)&ldsB1[w * 64 + j * 32 + q * 8 + hi * 4];
                #pragma unroll
                for (int rr = 0; rr < 4; ++rr) {
                    acc[0][j][q * 4 + rr] = b[rr];
                    acc[1][j][q * 4 + rr] = b[rr];
                }
            }

        __builtin_amdgcn_s_setprio(1);
        #pragma unroll
        for (int kst = 0; kst < 8; ++kst) {
            bf16x8 a[2];
            #pragma unroll
            for (int i = 0; i < 2; ++i) {
                int s = kst * 2 + hi;     // logical 16B k-slot 0..31
                int off = ((i * 32 + l31) << 8) + ((s & 16) << 3) + (((s & 15) << 3) ^ swz3);
                a[i] = *(const bf16x8*)&bufc[off];
            }
            #pragma unroll
            for (int i = 0; i < 2; ++i)
                #pragma unroll
                for (int j = 0; j < 2; ++j)
                    acc[i][j] = __builtin_amdgcn_mfma_f32_32x32x16_bf16(
                        *(const bf16x8*)&breg[j][kst], a[i], acc[i][j], 0, 0, 0);
        }
        __builtin_amdgcn_s_setprio(0);

        // issue next tile's gathers (HBM latency hides under kst 8..15)
        ISSUE_GATHER(cur ^ 1);
        asm volatile("" ::: "memory");

        __builtin_amdgcn_s_setprio(1);
        #pragma unroll
        for (int kst = 8; kst < 16; ++kst) {
            bf16x8 a[2];
            #pragma unroll
            for (int i = 0; i < 2; ++i) {
                int s = kst * 2 + hi;
                int off = ((i * 32 + l31) << 8) + ((s & 16) << 3) + (((s & 15) << 3) ^ swz3);
                a[i] = *(const bf16x8*)&bufc[off];
            }
            #pragma unroll
            for (int i = 0; i < 2; ++i)
                #pragma unroll
                for (int j = 0; j < 2; ++j)
                    acc[i][j] = __builtin_amdgcn_mfma_f32_32x32x16_bf16(
                        *(const bf16x8*)&breg[j][kst], a[i], acc[i][j], 0, 0, 0);
        }
        __builtin_amdgcn_s_setprio(0);

        // tail: idx for tile t+2G (consumed by NEXT iter's gather-issue)
        {
            int tt = t + 2 * G;
            #pragma unroll
            for (int q = 0; q < 4; ++q) {
                int e = tt * 64 + w * 8 + q * 2 + hi;
                e = (e < E) ? e : (E - 1);
                ival[q] = ei[side * E + e];
            }
        }
        asm volatile("" ::: "memory");  // pin: epilogue atomics AFTER idx

        // epilogue: y-partial = sum_{h in slice} relu(acc)*w2 ;
        // in-reg over (j,reg) + 1 shuffle (xor32); 2 atomics (hi==0 lanes)
        float s2[2];
        #pragma unroll
        for (int i = 0; i < 2; ++i) {
            float s = 0.f;
            #pragma unroll
            for (int j = 0; j < 2; ++j)
                #pragma unroll
                for (int q = 0; q < 4; ++q) {
                    f32x4 w2q = *(const f32x4*)&ldsW2[w * 64 + j * 32 + q * 8 + hi * 4];
                    #pragma unroll
                    for (int rr = 0; rr < 4; ++rr)
                        s = fmaf(fmaxf(acc[i][j][q * 4 + rr], 0.f), w2q[rr], s);
                }
            s += __shfl_xor(s, 32);
            s2[i] = s;
        }
        #pragma unroll
        for (int i = 0; i < 2; ++i) {
            int e = t * 64 + i * 32 + l31;
            if (hi == 0 && e < E) atomicAdd(&out[e], s2[i]);
        }

        cur ^= 1;
    }
#undef ISSUE_GATHER
}

extern "C" void kernel_launch(void* const* d_in, const int* in_sizes, int n_in,
                              void* d_out, int out_size, void* d_ws, size_t ws_size,
                              hipStream_t stream) {
    const float* z  = (const float*)d_in[0];
    const int*   ei = (const int*)d_in[1];
    const float* W1 = (const float*)d_in[2];
    const float* b1 = (const float*)d_in[3];
    const float* W2 = (const float*)d_in[4];
    const float* b2 = (const float*)d_in[5];
    float* out = (float*)d_out;

    const int E  = in_sizes[1] / 2;   // 500000
    const int NZ = in_sizes[0];       // 6400000 = N*D

    unsigned short* zb  = (unsigned short*)d_ws;       // 12.8 MB
    unsigned short* w1s = zb + NZ;                     // 256 KB (swizzled W1)

    prep_kernel<<<2048, 256, 0, stream>>>(z, W1, b2, zb, w1s, out, NZ / 4, E / 4);

    const int ntiles = (E + 63) / 64;                  // 7813
    int grid = 256;                                    // persistent, 1 block/CU
    edge_mlp_kernel<<<grid, 512, 0, stream>>>(ei, zb, w1s, b1, W2, out, E, ntiles);
}